// Round 4
// baseline (236.262 us; speedup 1.0000x reference)
//
#include <hip/hip_runtime.h>

typedef short s16x8 __attribute__((ext_vector_type(8)));
typedef float f32x4 __attribute__((ext_vector_type(4)));
typedef float f32x16 __attribute__((ext_vector_type(16)));

#define B_ 4
#define C_ 256
#define S_ 4096
#define LOG2E 1.44269504088896f
#define M2 32.0f   // fixed base-2 softmax offset: p = 2^(s' - M2)

#if __has_builtin(__builtin_amdgcn_exp2f)
#define EXP2(x) __builtin_amdgcn_exp2f(x)
#else
#define EXP2(x) __exp2f(x)
#endif

// RNE float -> bf16
__device__ __forceinline__ unsigned short f2b(float f) {
  union { float f; unsigned u; } v; v.f = f;
  unsigned r = v.u + 0x7fffu + ((v.u >> 16) & 1u);
  return (unsigned short)(r >> 16);
}
// cheap round-half-up float -> bf16 (hot loop)
__device__ __forceinline__ unsigned short f2b_fast(float f) {
  union { float f; unsigned u; } v; v.f = f;
  return (unsigned short)((v.u + 0x8000u) >> 16);
}
// 16B LDS load at 8B alignment
__device__ __forceinline__ s16x8 lds_ld8(const unsigned short* p) {
  union { s16x8 v; uint2 u[2]; } r;
  r.u[0] = *(const uint2*)p;
  r.u[1] = *(const uint2*)(p + 4);
  return r.v;
}

// ---- weight prep: fp32 -> bf16 MFMA A-fragment order ------------------------
// Wvf:  [cg 4][mt 2][ks16 16][lane 64][e 8]; elem = Wv[cg*64+mt*32+(lane&31)][ks16*16+(lane>>5)*8+e]
// Wqkf: [mt 2][ks16 16][lane 64][e 8];       mt=0 -> Wq*LOG2E, mt=1 -> Wk
__global__ __launch_bounds__(256)
void prep_kernel(const float* __restrict__ wq, const float* __restrict__ wk,
                 const float* __restrict__ wv,
                 unsigned short* __restrict__ Wvf, unsigned short* __restrict__ Wqkf) {
  const int G = (blockIdx.x * 256 + threadIdx.x) * 4;   // 4 consecutive elems
  union { unsigned short us[4]; uint2 u2; } pk;
  if (G < 65536) {
    const int e0 = G & 7, lane = (G >> 3) & 63, ks16 = (G >> 9) & 15;
    const int mt = (G >> 13) & 1, cg = G >> 14;
    const int row = cg * 64 + mt * 32 + (lane & 31);
    const int k   = ks16 * 16 + (lane >> 5) * 8 + e0;
    f32x4 v = *(const f32x4*)(wv + (size_t)row * 256 + k);
    #pragma unroll
    for (int i = 0; i < 4; ++i) pk.us[i] = f2b(v[i]);
    *(uint2*)(Wvf + G) = pk.u2;
  } else {
    const int H = G - 65536;
    const int e0 = H & 7, lane = (H >> 3) & 63, ks16 = (H >> 9) & 15;
    const int mt = (H >> 13) & 1;
    const int row = lane & 31;
    const int k   = ks16 * 16 + (lane >> 5) * 8 + e0;
    const float* src = mt ? wk : wq;
    f32x4 v = *(const f32x4*)(src + (size_t)row * 256 + k);
    if (mt == 0) v = v * LOG2E;
    #pragma unroll
    for (int i = 0; i < 4; ++i) pk.us[i] = f2b(v[i]);
    *(uint2*)(Wqkf + H) = pk.u2;
  }
}

// ---- fused QKV projection (MFMA, frag-order weights from global) ------------
// type==0: 64 out rows = {Q 0-31 (LOG2E-folded), K 0-31}; type==1: all 256 V ch.
// Qb,Kb: [B][S][32] bf16.  Vf: [b][jt][cg][vv][kb][lane][8] frag tiles.
__global__ __launch_bounds__(256, 4)
void proj_kernel(const float* __restrict__ x, const float* __restrict__ orig,
                 const float* __restrict__ bq, const float* __restrict__ bk,
                 const float* __restrict__ bv,
                 const unsigned short* __restrict__ Wqkf,
                 const unsigned short* __restrict__ Wvf,
                 unsigned short* __restrict__ Qb, unsigned short* __restrict__ Kb,
                 unsigned short* __restrict__ Vf) {
  __shared__ union {
    unsigned short Sl[64 * 68];      // staging: src transposed [n][c]
    unsigned short Rv[4 * 64 * 68];  // V repack [cg][ch][j]
  } um;
  const int jt   = blockIdx.x >> 1;
  const int type = blockIdx.x & 1;
  const int b    = blockIdx.y;
  const int n0   = jt * 64;
  const int t    = threadIdx.x;
  const int L = t & 63, w = t >> 6;
  const int g = L >> 5, l32 = L & 31;
  const float* srcb = (type == 0 ? x : orig) + (size_t)b * C_ * S_;
  f32x16 acc0 = (f32x16)0.0f, acc1 = (f32x16)0.0f;
  f32x16 acc2 = (f32x16)0.0f, acc3 = (f32x16)0.0f;
  const int mt = w >> 1, nt = w & 1;   // QK roles
  const int cg = w;                    // V role

  for (int kc = 0; kc < 4; ++kc) {
    const int k0 = kc * 64;
    __syncthreads();
    { // stage src transposed (fp32 -> bf16)
      const int c4s = (t >> 4) * 4;
      const int n4  = (t & 15) * 4;
      f32x4 v0 = *(const f32x4*)(srcb + (size_t)(k0 + c4s + 0) * S_ + n0 + n4);
      f32x4 v1 = *(const f32x4*)(srcb + (size_t)(k0 + c4s + 1) * S_ + n0 + n4);
      f32x4 v2 = *(const f32x4*)(srcb + (size_t)(k0 + c4s + 2) * S_ + n0 + n4);
      f32x4 v3 = *(const f32x4*)(srcb + (size_t)(k0 + c4s + 3) * S_ + n0 + n4);
      #pragma unroll
      for (int k = 0; k < 4; ++k) {
        union { unsigned short us[4]; uint2 u2; } pk;
        pk.us[0] = f2b(v0[k]); pk.us[1] = f2b(v1[k]);
        pk.us[2] = f2b(v2[k]); pk.us[3] = f2b(v3[k]);
        *(uint2*)&um.Sl[(n4 + k) * 68 + c4s] = pk.u2;
      }
    }
    __syncthreads();
    if (type == 0) {
      #pragma unroll
      for (int ks = 0; ks < 4; ++ks) {
        const int ks16 = kc * 4 + ks;
        s16x8 af = *(const s16x8*)(Wqkf + ((size_t)(mt * 16 + ks16) * 64 + L) * 8);
        s16x8 bf = lds_ld8(&um.Sl[(nt * 32 + l32) * 68 + ks * 16 + g * 8]);
        acc0 = __builtin_amdgcn_mfma_f32_32x32x16_bf16(af, bf, acc0, 0, 0, 0);
      }
    } else {
      #pragma unroll
      for (int ks = 0; ks < 4; ++ks) {
        const int ks16 = kc * 4 + ks;
        s16x8 af0 = *(const s16x8*)(Wvf + ((size_t)((cg * 2 + 0) * 16 + ks16) * 64 + L) * 8);
        s16x8 af1 = *(const s16x8*)(Wvf + ((size_t)((cg * 2 + 1) * 16 + ks16) * 64 + L) * 8);
        s16x8 bf0 = lds_ld8(&um.Sl[l32 * 68 + ks * 16 + g * 8]);
        s16x8 bf1 = lds_ld8(&um.Sl[(32 + l32) * 68 + ks * 16 + g * 8]);
        acc0 = __builtin_amdgcn_mfma_f32_32x32x16_bf16(af0, bf0, acc0, 0, 0, 0);
        acc1 = __builtin_amdgcn_mfma_f32_32x32x16_bf16(af0, bf1, acc1, 0, 0, 0);
        acc2 = __builtin_amdgcn_mfma_f32_32x32x16_bf16(af1, bf0, acc2, 0, 0, 0);
        acc3 = __builtin_amdgcn_mfma_f32_32x32x16_bf16(af1, bf1, acc3, 0, 0, 0);
      }
    }
  }
  __syncthreads();
  if (type == 0) {
    unsigned short* Rl = um.Sl;
    const int n = nt * 32 + l32;
    #pragma unroll
    for (int reg = 0; reg < 16; ++reg) {
      const int rr = (reg & 3) + 8 * (reg >> 2) + 4 * g;
      const float val = (mt == 0) ? acc0[reg] + bq[rr] * LOG2E : acc0[reg] + bk[rr];
      Rl[n * 68 + mt * 32 + rr] = f2b(val);
    }
    __syncthreads();
    const int nn = t >> 2, ch0 = (t & 3) * 16;
    s16x8 a = lds_ld8(Rl + nn * 68 + ch0);
    s16x8 c = lds_ld8(Rl + nn * 68 + ch0 + 8);
    unsigned short* dst = (ch0 < 32)
        ? Qb + ((size_t)b * S_ + n0 + nn) * 32 + ch0
        : Kb + ((size_t)b * S_ + n0 + nn) * 32 + (ch0 - 32);
    *(s16x8*)dst = a;
    *(s16x8*)(dst + 8) = c;
  } else {
    // dump accs -> Rv[cg][ch][j]
    #pragma unroll
    for (int mi = 0; mi < 2; ++mi)
      #pragma unroll
      for (int ni = 0; ni < 2; ++ni) {
        const f32x16 a = (mi == 0) ? (ni == 0 ? acc0 : acc1) : (ni == 0 ? acc2 : acc3);
        #pragma unroll
        for (int reg = 0; reg < 16; ++reg) {
          const int rr = (reg & 3) + 8 * (reg >> 2) + 4 * g;
          const int ch = mi * 32 + rr;
          um.Rv[(cg * 64 + ch) * 68 + ni * 32 + l32] = f2b(a[reg] + bv[cg * 64 + ch]);
        }
      }
    __syncthreads();
    unsigned short* Vtile = Vf + (size_t)(b * 64 + jt) * 4 * 4096;
    #pragma unroll
    for (int k = 0; k < 8; ++k) {
      const int cI = k * 256 + t;           // 0..2047 16B-chunks
      const int cgc = cI >> 9, r = cI & 511;
      const int vv = r >> 8, kb = (r >> 6) & 3, Lf = r & 63;
      const int chl = vv * 32 + (Lf & 31);
      const int jj  = kb * 16 + (Lf >> 5) * 8;
      s16x8 v = lds_ld8(&um.Rv[(cgc * 64 + chl) * 68 + jj]);
      *(s16x8*)(Vtile + (size_t)cI * 8) = v;
    }
  }
}

// ---- flash attention: single-barrier software-pipelined loop ----------------
// 512 threads, i-tile 64, grid 256. Body n: [vf(n-1) loads] [Phase A(n) ->
// P[n&1], K(n+1) prefetch] [Phase B(n-1) from P[(n-1)&1]] one barrier.
union FlashU {
  unsigned short P[2][64 * 68];   // double-buffered probabilities
  float scr[2][32 * 258];         // epilogue transpose
};

__global__ __launch_bounds__(512, 4)
void flash_kernel(const unsigned short* __restrict__ Qb,
                  const unsigned short* __restrict__ Kb,
                  const unsigned short* __restrict__ Vf,
                  const float* __restrict__ inp,
                  const float* __restrict__ gamma,
                  float* __restrict__ out) {
  __shared__ FlashU sm;
  __shared__ float lpart[2][64];
  __shared__ float invl[64];
  const int l  = blockIdx.x;
  const int b  = (l & 7) >> 1;                       // XCD pair per batch
  const int i0 = ((l >> 3) * 2 + (l & 1)) * 64;
  const int t  = threadIdx.x;
  const int L = t & 63, w = t >> 6;
  const int q4 = L >> 4, c16 = L & 15;
  const int g  = L >> 5, l32 = L & 31;
  const int rh = w & 3, jh = w >> 2;                 // phase A role
  const int cg = w & 3, dup = w >> 2;                // phase B role
  const float gam = gamma[0];
  const unsigned short* Kbase = Kb + (size_t)b * S_ * 32;
  const unsigned short* Vbb   = Vf + (size_t)b * 64 * 4 * 4096;
  const s16x8 qf = *(const s16x8*)(Qb + ((size_t)b * S_ + i0 + rh * 16 + c16) * 32 + q4 * 8);

  f32x16 acc00 = (f32x16)0.0f, acc01 = (f32x16)0.0f;
  f32x16 acc10 = (f32x16)0.0f, acc11 = (f32x16)0.0f;
  float lp[4] = {0.f, 0.f, 0.f, 0.f};
  s16x8 vf00, vf01, vf10, vf11;
  s16x8 kc0 = *(const s16x8*)(Kbase + (size_t)(jh * 32 + c16) * 32 + q4 * 8);
  s16x8 kc1 = *(const s16x8*)(Kbase + (size_t)(jh * 32 + 16 + c16) * 32 + q4 * 8);

  for (int n = 0; n < 64; ++n) {
    // V frags for tile n-1 (consumed by Phase B at end of this body)
    if (n > 0) {
      const unsigned short* vbase = Vbb + (size_t)((n - 1) * 4 + cg) * 4096;
      vf00 = *(const s16x8*)(vbase + (dup * 2 + 0) * 512 + L * 8);
      vf01 = *(const s16x8*)(vbase + 2048 + (dup * 2 + 0) * 512 + L * 8);
      vf10 = *(const s16x8*)(vbase + (dup * 2 + 1) * 512 + L * 8);
      vf11 = *(const s16x8*)(vbase + 2048 + (dup * 2 + 1) * 512 + L * 8);
    }
    // ---- Phase A(n)
    f32x4 cinit = (f32x4)(-M2);
    f32x4 s0 = __builtin_amdgcn_mfma_f32_16x16x32_bf16(qf, kc0, cinit, 0, 0, 0);
    f32x4 s1 = __builtin_amdgcn_mfma_f32_16x16x32_bf16(qf, kc1, cinit, 0, 0, 0);
    if (n < 63) {   // prefetch K(n+1); completes by the barrier
      const size_t jn = (size_t)(n + 1) * 64;
      kc0 = *(const s16x8*)(Kbase + (jn + jh * 32 + c16) * 32 + q4 * 8);
      kc1 = *(const s16x8*)(Kbase + (jn + jh * 32 + 16 + c16) * 32 + q4 * 8);
    }
    unsigned short* Pw = sm.P[n & 1];
    #pragma unroll
    for (int r = 0; r < 4; ++r) {
      const float p0 = EXP2(s0[r]);
      const float p1 = EXP2(s1[r]);
      lp[r] += p0 + p1;
      const int row = rh * 16 + q4 * 4 + r;
      Pw[row * 68 + jh * 32 + c16]      = f2b_fast(p0);
      Pw[row * 68 + jh * 32 + 16 + c16] = f2b_fast(p1);
    }
    // ---- Phase B(n-1)
    if (n > 0) {
      const unsigned short* Pr = sm.P[(n - 1) & 1];
      {
        const int ko = (dup * 2 + 0) * 16 + g * 8;
        const s16x8 pf0 = lds_ld8(Pr + l32 * 68 + ko);
        const s16x8 pf1 = lds_ld8(Pr + (32 + l32) * 68 + ko);
        acc00 = __builtin_amdgcn_mfma_f32_32x32x16_bf16(pf0, vf00, acc00, 0, 0, 0);
        acc01 = __builtin_amdgcn_mfma_f32_32x32x16_bf16(pf0, vf01, acc01, 0, 0, 0);
        acc10 = __builtin_amdgcn_mfma_f32_32x32x16_bf16(pf1, vf00, acc10, 0, 0, 0);
        acc11 = __builtin_amdgcn_mfma_f32_32x32x16_bf16(pf1, vf01, acc11, 0, 0, 0);
      }
      {
        const int ko = (dup * 2 + 1) * 16 + g * 8;
        const s16x8 pf0 = lds_ld8(Pr + l32 * 68 + ko);
        const s16x8 pf1 = lds_ld8(Pr + (32 + l32) * 68 + ko);
        acc00 = __builtin_amdgcn_mfma_f32_32x32x16_bf16(pf0, vf10, acc00, 0, 0, 0);
        acc01 = __builtin_amdgcn_mfma_f32_32x32x16_bf16(pf0, vf11, acc01, 0, 0, 0);
        acc10 = __builtin_amdgcn_mfma_f32_32x32x16_bf16(pf1, vf10, acc10, 0, 0, 0);
        acc11 = __builtin_amdgcn_mfma_f32_32x32x16_bf16(pf1, vf11, acc11, 0, 0, 0);
      }
    }
    __syncthreads();
  }
  // ---- tail: Phase B(63)
  {
    const unsigned short* vbase = Vbb + (size_t)(63 * 4 + cg) * 4096;
    vf00 = *(const s16x8*)(vbase + (dup * 2 + 0) * 512 + L * 8);
    vf01 = *(const s16x8*)(vbase + 2048 + (dup * 2 + 0) * 512 + L * 8);
    vf10 = *(const s16x8*)(vbase + (dup * 2 + 1) * 512 + L * 8);
    vf11 = *(const s16x8*)(vbase + 2048 + (dup * 2 + 1) * 512 + L * 8);
    const unsigned short* Pr = sm.P[1];
    {
      const int ko = (dup * 2 + 0) * 16 + g * 8;
      const s16x8 pf0 = lds_ld8(Pr + l32 * 68 + ko);
      const s16x8 pf1 = lds_ld8(Pr + (32 + l32) * 68 + ko);
      acc00 = __builtin_amdgcn_mfma_f32_32x32x16_bf16(pf0, vf00, acc00, 0, 0, 0);
      acc01 = __builtin_amdgcn_mfma_f32_32x32x16_bf16(pf0, vf01, acc01, 0, 0, 0);
      acc10 = __builtin_amdgcn_mfma_f32_32x32x16_bf16(pf1, vf00, acc10, 0, 0, 0);
      acc11 = __builtin_amdgcn_mfma_f32_32x32x16_bf16(pf1, vf01, acc11, 0, 0, 0);
    }
    {
      const int ko = (dup * 2 + 1) * 16 + g * 8;
      const s16x8 pf0 = lds_ld8(Pr + l32 * 68 + ko);
      const s16x8 pf1 = lds_ld8(Pr + (32 + l32) * 68 + ko);
      acc00 = __builtin_amdgcn_mfma_f32_32x32x16_bf16(pf0, vf10, acc00, 0, 0, 0);
      acc01 = __builtin_amdgcn_mfma_f32_32x32x16_bf16(pf0, vf11, acc01, 0, 0, 0);
      acc10 = __builtin_amdgcn_mfma_f32_32x32x16_bf16(pf1, vf10, acc10, 0, 0, 0);
      acc11 = __builtin_amdgcn_mfma_f32_32x32x16_bf16(pf1, vf11, acc11, 0, 0, 0);
    }
  }
  // ---- l reduction
  #pragma unroll
  for (int r = 0; r < 4; ++r) {
    float v = lp[r];
    #pragma unroll
    for (int d = 1; d < 16; d <<= 1) v += __shfl_xor(v, d, 64);
    lp[r] = v;
  }
  if (c16 == 0) {
    #pragma unroll
    for (int r = 0; r < 4; ++r) lpart[jh][rh * 16 + q4 * 4 + r] = lp[r];
  }
  __syncthreads();
  if (t < 64) invl[t] = gam / (lpart[0][t] + lpart[1][t]);
  // ---- epilogue
  #pragma unroll
  for (int h = 0; h < 2; ++h) {
    const f32x16 a0 = h ? acc10 : acc00;
    const f32x16 a1 = h ? acc11 : acc01;
    float* pl = sm.scr[dup];
    #pragma unroll
    for (int reg = 0; reg < 16; ++reg) {
      const int rr = (reg & 3) + 8 * (reg >> 2) + 4 * g;
      pl[rr * 258 + cg * 64 + l32]      = a0[reg];
      pl[rr * 258 + cg * 64 + 32 + l32] = a1[reg];
    }
    __syncthreads();
    const int ch = t >> 1;
    const int il16 = (t & 1) * 16;
    #pragma unroll
    for (int q = 0; q < 4; ++q) {
      const int iloc = il16 + q * 4;
      const size_t gi = ((size_t)b * C_ + ch) * S_ + i0 + h * 32 + iloc;
      const f32x4 iv = *(const f32x4*)(inp + gi);
      f32x4 o;
      #pragma unroll
      for (int k = 0; k < 4; ++k) {
        const int il = iloc + k;
        o[k] = (sm.scr[0][il * 258 + ch] + sm.scr[1][il * 258 + ch]) * invl[h * 32 + il] + iv[k];
      }
      *(f32x4*)(out + gi) = o;
    }
    __syncthreads();
  }
}

// ---- launch -----------------------------------------------------------------
extern "C" void kernel_launch(void* const* d_in, const int* in_sizes, int n_in,
                              void* d_out, int out_size, void* d_ws, size_t ws_size,
                              hipStream_t stream) {
  const float* inp   = (const float*)d_in[0];
  const float* orig  = (const float*)d_in[1];
  const float* wq    = (const float*)d_in[2];
  const float* bq    = (const float*)d_in[3];
  const float* wk    = (const float*)d_in[4];
  const float* bk    = (const float*)d_in[5];
  const float* wv    = (const float*)d_in[6];
  const float* bv    = (const float*)d_in[7];
  const float* gamma = (const float*)d_in[8];
  float* out = (float*)d_out;

  unsigned short* Qb = (unsigned short*)d_ws;            // [B][S][32] bf16, 1 MB
  unsigned short* Kb = Qb + (size_t)B_ * S_ * 32;        // [B][S][32] bf16, 1 MB
  unsigned short* Vf = Kb + (size_t)B_ * S_ * 32;        // frag-tiled V, 8 MB
  // weight fragments live in the tail of d_out: written by prep, read by proj,
  // overwritten only later by flash (stream-ordered, so race-free)
  unsigned short* Wvf  = (unsigned short*)((char*)d_out + (size_t)out_size * 4 - 262144);
  unsigned short* Wqkf = Wvf + 65536;

  prep_kernel<<<80, 256, 0, stream>>>(wq, wk, wv, Wvf, Wqkf);
  proj_kernel<<<dim3(128, 4), 256, 0, stream>>>(inp, orig, bq, bk, bv, Wqkf, Wvf, Qb, Kb, Vf);
  flash_kernel<<<256, 512, 0, stream>>>(Qb, Kb, Vf, inp, gamma, out);
}

// Round 6
// 172.608 us; speedup vs baseline: 1.3688x; 1.3688x over previous
//
#include <hip/hip_runtime.h>

typedef short s16x8 __attribute__((ext_vector_type(8)));
typedef float f32x4 __attribute__((ext_vector_type(4)));
typedef float f32x16 __attribute__((ext_vector_type(16)));

#define B_ 4
#define C_ 256
#define S_ 4096
#define LOG2E 1.44269504088896f
#define M2 32.0f   // fixed base-2 softmax offset: p = 2^(s' - M2)

#if __has_builtin(__builtin_amdgcn_exp2f)
#define EXP2(x) __builtin_amdgcn_exp2f(x)
#else
#define EXP2(x) __exp2f(x)
#endif

// RNE float -> bf16
__device__ __forceinline__ unsigned short f2b(float f) {
  union { float f; unsigned u; } v; v.f = f;
  unsigned r = v.u + 0x7fffu + ((v.u >> 16) & 1u);
  return (unsigned short)(r >> 16);
}
// cheap round-half-up float -> bf16 (hot loop)
__device__ __forceinline__ unsigned short f2b_fast(float f) {
  union { float f; unsigned u; } v; v.f = f;
  return (unsigned short)((v.u + 0x8000u) >> 16);
}
// 16B LDS load at 8B alignment
__device__ __forceinline__ s16x8 lds_ld8(const unsigned short* p) {
  union { s16x8 v; uint2 u[2]; } r;
  r.u[0] = *(const uint2*)p;
  r.u[1] = *(const uint2*)(p + 4);
  return r.v;
}

// ---- weight prep: fp32 -> bf16 MFMA A-fragment order ------------------------
// Wvf:  [cg 4][mt 2][ks16 16][lane 64][e 8]; elem = Wv[cg*64+mt*32+(lane&31)][ks16*16+(lane>>5)*8+e]
// Wqkf: [mt 2][ks16 16][lane 64][e 8];       mt=0 -> Wq*LOG2E, mt=1 -> Wk
__global__ __launch_bounds__(256)
void prep_kernel(const float* __restrict__ wq, const float* __restrict__ wk,
                 const float* __restrict__ wv,
                 unsigned short* __restrict__ Wvf, unsigned short* __restrict__ Wqkf) {
  const int G = (blockIdx.x * 256 + threadIdx.x) * 4;   // 4 consecutive elems
  union { unsigned short us[4]; uint2 u2; } pk;
  if (G < 65536) {
    const int e0 = G & 7, lane = (G >> 3) & 63, ks16 = (G >> 9) & 15;
    const int mt = (G >> 13) & 1, cg = G >> 14;
    const int row = cg * 64 + mt * 32 + (lane & 31);
    const int k   = ks16 * 16 + (lane >> 5) * 8 + e0;
    f32x4 v = *(const f32x4*)(wv + (size_t)row * 256 + k);
    #pragma unroll
    for (int i = 0; i < 4; ++i) pk.us[i] = f2b(v[i]);
    *(uint2*)(Wvf + G) = pk.u2;
  } else {
    const int H = G - 65536;
    const int e0 = H & 7, lane = (H >> 3) & 63, ks16 = (H >> 9) & 15;
    const int mt = (H >> 13) & 1;
    const int row = lane & 31;
    const int k   = ks16 * 16 + (lane >> 5) * 8 + e0;
    const float* src = mt ? wk : wq;
    f32x4 v = *(const f32x4*)(src + (size_t)row * 256 + k);
    if (mt == 0) v = v * LOG2E;
    #pragma unroll
    for (int i = 0; i < 4; ++i) pk.us[i] = f2b(v[i]);
    *(uint2*)(Wqkf + H) = pk.u2;
  }
}

// ---- Q/K projection ---------------------------------------------------------
// grid (64 jt, 4 b), 256 threads. Out: Qb,Kb [B][S][32] bf16.
__global__ __launch_bounds__(256, 2)
void qkproj_kernel(const float* __restrict__ x,
                   const float* __restrict__ bq, const float* __restrict__ bk,
                   const unsigned short* __restrict__ Wqkf,
                   unsigned short* __restrict__ Qb, unsigned short* __restrict__ Kb) {
  __shared__ union {
    unsigned short Sl[64 * 260];   // [n][c] bf16
    unsigned short Rl[64 * 68];    // [n][ch] repack
  } um;
  const int jt = blockIdx.x, b = blockIdx.y;
  const int n0 = jt * 64;
  const int t = threadIdx.x;
  const int L = t & 63, w = t >> 6;
  const int g = L >> 5, l32 = L & 31;
  const float* xb = x + (size_t)b * C_ * S_;
  #pragma unroll
  for (int hp = 0; hp < 2; ++hp) {
    const int c8 = hp * 128 + (t >> 4) * 8;
    const int n4 = (t & 15) * 4;
    f32x4 v[8];
    #pragma unroll
    for (int j = 0; j < 8; ++j)
      v[j] = *(const f32x4*)(xb + (size_t)(c8 + j) * S_ + n0 + n4);
    #pragma unroll
    for (int k = 0; k < 4; ++k) {
      union { unsigned short us[8]; uint2 u2[2]; } pk;
      #pragma unroll
      for (int j = 0; j < 8; ++j) pk.us[j] = f2b(v[j][k]);
      *(uint2*)&um.Sl[(n4 + k) * 260 + c8]     = pk.u2[0];
      *(uint2*)&um.Sl[(n4 + k) * 260 + c8 + 4] = pk.u2[1];
    }
  }
  __syncthreads();
  const int mt = w >> 1, nt = w & 1;
  f32x16 acc = (f32x16)0.0f;
  #pragma unroll
  for (int ks = 0; ks < 16; ++ks) {
    s16x8 af = *(const s16x8*)(Wqkf + ((size_t)(mt * 16 + ks) * 64 + L) * 8);
    s16x8 bf = lds_ld8(&um.Sl[(nt * 32 + l32) * 260 + ks * 16 + g * 8]);
    acc = __builtin_amdgcn_mfma_f32_32x32x16_bf16(af, bf, acc, 0, 0, 0);
  }
  __syncthreads();
  const int n = nt * 32 + l32;
  #pragma unroll
  for (int reg = 0; reg < 16; ++reg) {
    const int rr = (reg & 3) + 8 * (reg >> 2) + 4 * g;
    const float val = (mt == 0) ? acc[reg] + bq[rr] * LOG2E : acc[reg] + bk[rr];
    um.Rl[n * 68 + mt * 32 + rr] = f2b(val);
  }
  __syncthreads();
  const int nn = t >> 2, ch0 = (t & 3) * 16;
  s16x8 a = lds_ld8(um.Rl + nn * 68 + ch0);
  s16x8 cvec = lds_ld8(um.Rl + nn * 68 + ch0 + 8);
  unsigned short* dst = (ch0 < 32)
      ? Qb + ((size_t)b * S_ + n0 + nn) * 32 + ch0
      : Kb + ((size_t)b * S_ + n0 + nn) * 32 + (ch0 - 32);
  *(s16x8*)dst = a;
  *(s16x8*)(dst + 8) = cvec;
}

// ---- V projection -----------------------------------------------------------
// grid (64 jt, 4 b), 512 threads; wave w owns ch w*32..+32 x 64 n.
// Vf frag tiles [b*64+jt][cg][vv][kb][lane][8]; j stored PI-PERMUTED within
// the 64-tile: pi(j) = (j&15)*4 + (j>>5)*2 + ((j>>4)&1). flash's P uses the
// same permutation, so PV is unaffected.
__global__ __launch_bounds__(512, 2)
void vproj_kernel(const float* __restrict__ orig, const float* __restrict__ bv,
                  const unsigned short* __restrict__ Wvf,
                  unsigned short* __restrict__ Vf) {
  __shared__ union {
    unsigned short Sl[64 * 260];   // [n][c] bf16
    unsigned short Rv[256 * 68];   // [ch][pi(j)] repack
  } um;
  const int jt = blockIdx.x, b = blockIdx.y;
  const int n0 = jt * 64;
  const int t = threadIdx.x;
  const int L = t & 63, w = t >> 6;
  const int g = L >> 5, l32 = L & 31;
  const float* ob = orig + (size_t)b * C_ * S_;
  {
    const int c8 = (t >> 4) * 8;   // 0..248
    const int n4 = (t & 15) * 4;
    f32x4 v[8];
    #pragma unroll
    for (int j = 0; j < 8; ++j)
      v[j] = *(const f32x4*)(ob + (size_t)(c8 + j) * S_ + n0 + n4);
    #pragma unroll
    for (int k = 0; k < 4; ++k) {
      union { unsigned short us[8]; uint2 u2[2]; } pk;
      #pragma unroll
      for (int j = 0; j < 8; ++j) pk.us[j] = f2b(v[j][k]);
      *(uint2*)&um.Sl[(n4 + k) * 260 + c8]     = pk.u2[0];
      *(uint2*)&um.Sl[(n4 + k) * 260 + c8 + 4] = pk.u2[1];
    }
  }
  __syncthreads();
  f32x16 acc0 = (f32x16)0.0f, acc1 = (f32x16)0.0f;
  #pragma unroll
  for (int ks = 0; ks < 16; ++ks) {
    s16x8 af  = *(const s16x8*)(Wvf + ((size_t)(w * 16 + ks) * 64 + L) * 8);
    s16x8 bf0 = lds_ld8(&um.Sl[l32 * 260 + ks * 16 + g * 8]);
    s16x8 bf1 = lds_ld8(&um.Sl[(32 + l32) * 260 + ks * 16 + g * 8]);
    acc0 = __builtin_amdgcn_mfma_f32_32x32x16_bf16(af, bf0, acc0, 0, 0, 0);
    acc1 = __builtin_amdgcn_mfma_f32_32x32x16_bf16(af, bf1, acc1, 0, 0, 0);
  }
  __syncthreads();
  // dump pi-permuted: acc0 covers j=l32, acc1 covers j=32+l32
  const int pi0 = (l32 & 15) * 4 + (l32 >> 4);   // pi(l32)
  #pragma unroll
  for (int reg = 0; reg < 16; ++reg) {
    const int rr = (reg & 3) + 8 * (reg >> 2) + 4 * g;
    const int ch = w * 32 + rr;
    const float bias = bv[ch];
    um.Rv[ch * 68 + pi0]     = f2b(acc0[reg] + bias);   // j = l32      -> jh=0
    um.Rv[ch * 68 + pi0 + 2] = f2b(acc1[reg] + bias);   // j = 32+l32   -> jh=1
  }
  __syncthreads();
  unsigned short* Vtile = Vf + (size_t)(b * 64 + jt) * 4 * 4096;
  #pragma unroll
  for (int k = 0; k < 4; ++k) {
    const int cI = k * 512 + t;            // 0..2047 16B-chunks
    const int cgc = cI >> 9, r = cI & 511;
    const int vv = r >> 8, kb = (r >> 6) & 3, Lf = r & 63;
    const int chl = cgc * 64 + vv * 32 + (Lf & 31);
    const int jj  = kb * 16 + (Lf >> 5) * 8;   // pi-space, contiguous
    s16x8 vvv = lds_ld8(&um.Rv[chl * 68 + jj]);
    *(s16x8*)(Vtile + (size_t)cI * 8) = vvv;
  }
}

// ---- flash attention: 128-j chunks, one barrier per chunk -------------------
// 512 threads, i-tile 64, grid 256 (1 block/CU). Body c:
//   [vf(c-1) global loads][K(c+1) global prefetch -> regs]
//   [Phase A(c): QK^T from kc regs, exp2, P(pi-packed b32)->buf c&1]
//   [Phase B(c-1): P x V frags]  one barrier.  kc <- kn.
struct FlashSmem {
  union {
    unsigned short P[2][64 * 132];   // 33792 B, dbuf, pi-permuted cols
    float scr[2][32 * 258];          // 66048 B, epilogue
  } u;
  float lpart[2][64];
  float invl[64];
};

__global__ __launch_bounds__(512, 2)
void flash_kernel(const unsigned short* __restrict__ Qb,
                  const unsigned short* __restrict__ Kb,
                  const unsigned short* __restrict__ Vf,
                  const float* __restrict__ inp,
                  const float* __restrict__ gamma,
                  float* __restrict__ out) {
  __shared__ FlashSmem sm;
  const int l  = blockIdx.x;
  const int b  = (l & 7) >> 1;                    // XCD pair per batch
  const int i0 = ((l >> 3) * 2 + (l & 1)) * 64;
  const int t  = threadIdx.x;
  const int L = t & 63, w = t >> 6;
  const int q4 = L >> 4, c16 = L & 15;
  const int g  = L >> 5, l32 = L & 31;
  const int rh = w & 3, jh = w >> 2;              // phase A role
  const int cg = w & 3, dup = w >> 2;             // phase B role (dup = j-64-tile)
  const float gam = gamma[0];
  const unsigned short* Kbb = Kb + (size_t)b * S_ * 32;
  const unsigned short* Vbb = Vf + (size_t)b * 64 * 4 * 4096;
  const s16x8 qf = *(const s16x8*)(Qb + ((size_t)b * S_ + i0 + rh * 16 + c16) * 32 + q4 * 8);

  f32x16 acc00 = (f32x16)0.0f, acc01 = (f32x16)0.0f;  // i 0..31 x ch {vv0,vv1}
  f32x16 acc10 = (f32x16)0.0f, acc11 = (f32x16)0.0f;  // i 32..63
  float lp[4] = {0.f, 0.f, 0.f, 0.f};

  // K fragments for chunk 0 (coalesced: lanes tile contiguous 1KB)
  s16x8 kc[4], kn[4];
  #pragma unroll
  for (int tt = 0; tt < 2; ++tt) {
    kc[tt * 2 + 0] = *(const s16x8*)(Kbb + (size_t)(tt * 64 + jh * 32 + c16) * 32 + q4 * 8);
    kc[tt * 2 + 1] = *(const s16x8*)(Kbb + (size_t)(tt * 64 + jh * 32 + 16 + c16) * 32 + q4 * 8);
  }

  for (int c = 0; c < 32; ++c) {
    // -- global loads issued at interval top
    s16x8 vf0[4], vf1[4];
    if (c > 0) {
      const unsigned short* vb = Vbb + (size_t)(((c - 1) * 2 + dup) * 4 + cg) * 4096;
      #pragma unroll
      for (int kb = 0; kb < 4; ++kb) {
        vf0[kb] = *(const s16x8*)(vb + kb * 512 + L * 8);
        vf1[kb] = *(const s16x8*)(vb + 2048 + kb * 512 + L * 8);
      }
    }
    if (c < 31) {
      const unsigned short* kbase = Kbb + (size_t)(c + 1) * 128 * 32;
      #pragma unroll
      for (int tt = 0; tt < 2; ++tt) {
        kn[tt * 2 + 0] = *(const s16x8*)(kbase + (size_t)(tt * 64 + jh * 32 + c16) * 32 + q4 * 8);
        kn[tt * 2 + 1] = *(const s16x8*)(kbase + (size_t)(tt * 64 + jh * 32 + 16 + c16) * 32 + q4 * 8);
      }
    }
    // -- Phase A(c): scores for 2 j-tiles of 64; pi-packed b32 P writes
    unsigned short* Pw = sm.u.P[c & 1];
    #pragma unroll
    for (int tt = 0; tt < 2; ++tt) {
      const f32x4 cinit = (f32x4)(-M2);
      f32x4 s0 = __builtin_amdgcn_mfma_f32_16x16x32_bf16(qf, kc[tt * 2 + 0], cinit, 0, 0, 0);
      f32x4 s1 = __builtin_amdgcn_mfma_f32_16x16x32_bf16(qf, kc[tt * 2 + 1], cinit, 0, 0, 0);
      #pragma unroll
      for (int r = 0; r < 4; ++r) {
        const float p0 = EXP2(s0[r]);   // j-half 0 -> pi even
        const float p1 = EXP2(s1[r]);   // j-half 1 -> pi odd
        lp[r] += p0 + p1;
        const int row = rh * 16 + q4 * 4 + r;
        const unsigned pack = (unsigned)f2b_fast(p0) | ((unsigned)f2b_fast(p1) << 16);
        *(unsigned*)&Pw[row * 132 + tt * 64 + c16 * 4 + jh * 2] = pack;
      }
    }
    // -- Phase B(c-1): wave (cg,dup) does 64 ch x 64 i over its 64-j tile
    if (c > 0) {
      const unsigned short* Pr = sm.u.P[(c - 1) & 1];
      #pragma unroll
      for (int kb = 0; kb < 4; ++kb) {
        const int ko = dup * 64 + kb * 16 + g * 8;
        const s16x8 pf0 = lds_ld8(Pr + l32 * 132 + ko);
        const s16x8 pf1 = lds_ld8(Pr + (32 + l32) * 132 + ko);
        acc00 = __builtin_amdgcn_mfma_f32_32x32x16_bf16(pf0, vf0[kb], acc00, 0, 0, 0);
        acc01 = __builtin_amdgcn_mfma_f32_32x32x16_bf16(pf0, vf1[kb], acc01, 0, 0, 0);
        acc10 = __builtin_amdgcn_mfma_f32_32x32x16_bf16(pf1, vf0[kb], acc10, 0, 0, 0);
        acc11 = __builtin_amdgcn_mfma_f32_32x32x16_bf16(pf1, vf1[kb], acc11, 0, 0, 0);
      }
    }
    __syncthreads();
    #pragma unroll
    for (int i = 0; i < 4; ++i) kc[i] = kn[i];
  }
  // -- tail: Phase B(31)
  {
    const unsigned short* vb = Vbb + (size_t)((62 + dup) * 4 + cg) * 4096;
    s16x8 vf0[4], vf1[4];
    #pragma unroll
    for (int kb = 0; kb < 4; ++kb) {
      vf0[kb] = *(const s16x8*)(vb + kb * 512 + L * 8);
      vf1[kb] = *(const s16x8*)(vb + 2048 + kb * 512 + L * 8);
    }
    const unsigned short* Pr = sm.u.P[1];
    #pragma unroll
    for (int kb = 0; kb < 4; ++kb) {
      const int ko = dup * 64 + kb * 16 + g * 8;
      const s16x8 pf0 = lds_ld8(Pr + l32 * 132 + ko);
      const s16x8 pf1 = lds_ld8(Pr + (32 + l32) * 132 + ko);
      acc00 = __builtin_amdgcn_mfma_f32_32x32x16_bf16(pf0, vf0[kb], acc00, 0, 0, 0);
      acc01 = __builtin_amdgcn_mfma_f32_32x32x16_bf16(pf0, vf1[kb], acc01, 0, 0, 0);
      acc10 = __builtin_amdgcn_mfma_f32_32x32x16_bf16(pf1, vf0[kb], acc10, 0, 0, 0);
      acc11 = __builtin_amdgcn_mfma_f32_32x32x16_bf16(pf1, vf1[kb], acc11, 0, 0, 0);
    }
  }
  // -- l reduction
  #pragma unroll
  for (int r = 0; r < 4; ++r) {
    float v = lp[r];
    #pragma unroll
    for (int d = 1; d < 16; d <<= 1) v += __shfl_xor(v, d, 64);
    lp[r] = v;
  }
  if (c16 == 0) {
    #pragma unroll
    for (int r = 0; r < 4; ++r) sm.lpart[jh][rh * 16 + q4 * 4 + r] = lp[r];
  }
  __syncthreads();   // tail P reads done before scr overwrites
  if (t < 64) sm.invl[t] = gam / (sm.lpart[0][t] + sm.lpart[1][t]);
  // -- epilogue: transpose via LDS, scale by gamma/l, add input
  #pragma unroll
  for (int h = 0; h < 2; ++h) {
    const f32x16 a0 = h ? acc10 : acc00;
    const f32x16 a1 = h ? acc11 : acc01;
    float* pl = sm.u.scr[dup];
    #pragma unroll
    for (int reg = 0; reg < 16; ++reg) {
      const int rr = (reg & 3) + 8 * (reg >> 2) + 4 * g;
      pl[rr * 258 + cg * 64 + l32]      = a0[reg];
      pl[rr * 258 + cg * 64 + 32 + l32] = a1[reg];
    }
    __syncthreads();   // scr ready (+ invl visible on first pass)
    const int ch = t >> 1;
    const int il16 = (t & 1) * 16;
    #pragma unroll
    for (int q = 0; q < 4; ++q) {
      const int iloc = il16 + q * 4;
      const size_t gi = ((size_t)b * C_ + ch) * S_ + i0 + h * 32 + iloc;
      const f32x4 iv = *(const f32x4*)(inp + gi);
      f32x4 o;
      #pragma unroll
      for (int k = 0; k < 4; ++k) {
        const int il = iloc + k;
        o[k] = (sm.u.scr[0][il * 258 + ch] + sm.u.scr[1][il * 258 + ch]) * sm.invl[h * 32 + il] + iv[k];
      }
      *(f32x4*)(out + gi) = o;
    }
    __syncthreads();
  }
}

// ---- launch -----------------------------------------------------------------
extern "C" void kernel_launch(void* const* d_in, const int* in_sizes, int n_in,
                              void* d_out, int out_size, void* d_ws, size_t ws_size,
                              hipStream_t stream) {
  const float* inp   = (const float*)d_in[0];
  const float* orig  = (const float*)d_in[1];
  const float* wq    = (const float*)d_in[2];
  const float* bq    = (const float*)d_in[3];
  const float* wk    = (const float*)d_in[4];
  const float* bk    = (const float*)d_in[5];
  const float* wv    = (const float*)d_in[6];
  const float* bv    = (const float*)d_in[7];
  const float* gamma = (const float*)d_in[8];
  float* out = (float*)d_out;

  unsigned short* Qb = (unsigned short*)d_ws;            // [B][S][32] bf16, 1 MB
  unsigned short* Kb = Qb + (size_t)B_ * S_ * 32;        // [B][S][32] bf16, 1 MB
  unsigned short* Vf = Kb + (size_t)B_ * S_ * 32;        // frag-tiled V, 8 MB
  // weight fragments in the tail of d_out: written by prep, read by projs,
  // overwritten only later by flash (stream-ordered, race-free)
  unsigned short* Wvf  = (unsigned short*)((char*)d_out + (size_t)out_size * 4 - 262144);
  unsigned short* Wqkf = Wvf + 65536;

  prep_kernel<<<80, 256, 0, stream>>>(wq, wk, wv, Wvf, Wqkf);
  qkproj_kernel<<<dim3(64, 4), 256, 0, stream>>>(inp, bq, bk, Wqkf, Qb, Kb);
  vproj_kernel<<<dim3(64, 4), 512, 0, stream>>>(orig, bv, Wvf, Vf);
  flash_kernel<<<256, 512, 0, stream>>>(Qb, Kb, Vf, inp, gamma, out);
}